// Round 1
// baseline (559.343 us; speedup 1.0000x reference)
//
#include <hip/hip_runtime.h>
#include <math.h>

#define BB 512
#define TT 1024
#define NS 50

__device__ __forceinline__ float wave_max_f(float v) {
    #pragma unroll
    for (int k = 32; k >= 1; k >>= 1) v = fmaxf(v, __shfl_xor(v, k, 64));
    return v;
}
__device__ __forceinline__ float wave_sum_f(float v) {
    #pragma unroll
    for (int k = 32; k >= 1; k >>= 1) v += __shfl_xor(v, k, 64);
    return v;
}
__device__ __forceinline__ int wave_sum_i(int v) {
    #pragma unroll
    for (int k = 32; k >= 1; k >>= 1) v += __shfl_xor(v, k, 64);
    return v;
}
// broadcast lane L's float to all lanes via v_readlane (VALU pipe, no LDS)
__device__ __forceinline__ float bcast(float v, int lane) {
    return __uint_as_float(__builtin_amdgcn_readlane(__float_as_uint(v), lane));
}

__global__ __launch_bounds__(64, 1) void crf_nll_kernel(
    const float* __restrict__ feat,    // (B, T, N)
    const float* __restrict__ trans,   // (N, N)
    const int*   __restrict__ tags,    // (B, T)
    const int*   __restrict__ mask,    // (B, T)
    float* __restrict__ out)           // (B,)
{
    const int b    = blockIdx.x;
    const int lane = threadIdx.x;     // lane == state j for the recursion
    const int j    = lane;
    const int jj   = (j < NS) ? j : 0;   // clamped index for safe loads

    // --- per-lane column of E = exp(trans): Ec[i] = exp(trans[i][j]) ---
    // exp(-10000) underflows to exactly 0 -> forbidden transitions vanish.
    float Ec[NS];
    #pragma unroll
    for (int i = 0; i < NS; ++i) {
        float e = __expf(trans[i * NS + jj]);   // coalesced: lanes read adjacent cols
        Ec[i] = (j < NS) ? e : 0.0f;
    }

    // --- sequence length (mask is a prefix of ones) ---
    int cnt = 0;
    for (int t = lane; t < TT; t += 64) cnt += mask[b * TT + t];
    const int len = wave_sum_i(cnt);   // uniform across wave; len >= T/2 >= 2

    const float* fb = feat + (size_t)b * TT * NS;

    // --- alpha init: alpha0[j] = trans[ROOT=0][j] + feat[b,0,j] ---
    float a = (j < NS) ? (trans[j] + fb[j]) : -INFINITY;
    float off = wave_max_f(a);   // finite (states >=2 have finite trans row 0)

    // --- forward recursion, t = 1 .. len-1 (alpha frozen past len) ---
    float f_next = fb[1 * NS + jj];
    for (int t = 1; t < len; ++t) {
        float f = f_next;
        int tn = (t + 1 < len) ? (t + 1) : t;
        f_next = fb[tn * NS + jj];                 // prefetch next step's feature

        float p = __expf(a - off);                 // p_i in lane i; lanes>=50: exp(-inf)=0

        float s0 = 0.f, s1 = 0.f, s2 = 0.f, s3 = 0.f;
        #pragma unroll
        for (int i = 0; i < 48; i += 4) {
            s0 = fmaf(bcast(p, i + 0), Ec[i + 0], s0);
            s1 = fmaf(bcast(p, i + 1), Ec[i + 1], s1);
            s2 = fmaf(bcast(p, i + 2), Ec[i + 2], s2);
            s3 = fmaf(bcast(p, i + 3), Ec[i + 3], s3);
        }
        s0 = fmaf(bcast(p, 48), Ec[48], s0);
        s1 = fmaf(bcast(p, 49), Ec[49], s1);
        float s = (s0 + s1) + (s2 + s3);

        // lanes >= 50 (and state 0): s == 0 -> log -> -inf, stays dead. Correct.
        a = f + off + __logf(s);

        if ((t & 3) == 0) off = wave_max_f(a);     // rescale: drift bounded ~40 << 88
    }

    // --- log_z = logsumexp_j(alpha[j] + trans[j][END=1]) ---
    float v = (j < NS) ? (a + trans[j * NS + 1]) : -INFINITY;
    float M = wave_max_f(v);
    float Z = wave_sum_f(__expf(v - M));           // exp(-inf - M) = 0
    float log_z = M + __logf(Z);

    // --- gold path score, lane-parallel over t ---
    // score = trans[0,tag0] + sum_{t=1}^{len-1} trans[tag_{t-1},tag_t]
    //       + sum_{t=0}^{len-1} feat[t, tag_t] + trans[tag_{len-1}, END]
    const int* tb = tags + (size_t)b * TT;
    float sc = 0.0f;
    for (int t = lane; t < len; t += 64) {
        int tg = tb[t];
        sc += fb[t * NS + tg];
        if (t >= 1) sc += trans[tb[t - 1] * NS + tg];
    }
    sc = wave_sum_f(sc);

    if (lane == 0) {
        int t0 = tb[0];
        int tl = tb[len - 1];
        sc += trans[t0] + trans[tl * NS + 1];
        out[b] = log_z - sc;
    }
}

extern "C" void kernel_launch(void* const* d_in, const int* in_sizes, int n_in,
                              void* d_out, int out_size, void* d_ws, size_t ws_size,
                              hipStream_t stream) {
    const float* feat  = (const float*)d_in[0];
    const float* trans = (const float*)d_in[1];
    const int*   tags  = (const int*)d_in[2];
    const int*   mask  = (const int*)d_in[3];
    float* out = (float*)d_out;
    crf_nll_kernel<<<dim3(BB), dim3(64), 0, stream>>>(feat, trans, tags, mask, out);
}

// Round 3
// 440.084 us; speedup vs baseline: 1.2710x; 1.2710x over previous
//
#include <hip/hip_runtime.h>
#include <math.h>

#define BB 512
#define TT 1024
#define NS 50

typedef _Float16 half2_t __attribute__((ext_vector_type(2)));

__device__ __forceinline__ half2_t pk_h2(float a, float b) {
    // cvt_pkrtz returns __fp16x2; bit-cast to _Float16x2 for fdot2
    auto r = __builtin_amdgcn_cvt_pkrtz(a, b);
    return __builtin_bit_cast(half2_t, r);
}

__device__ __forceinline__ float wave_max_f(float v) {
    #pragma unroll
    for (int k = 32; k >= 1; k >>= 1) v = fmaxf(v, __shfl_xor(v, k, 64));
    return v;
}
__device__ __forceinline__ float wave_sum_f(float v) {
    #pragma unroll
    for (int k = 32; k >= 1; k >>= 1) v += __shfl_xor(v, k, 64);
    return v;
}
__device__ __forceinline__ int wave_sum_i(int v) {
    #pragma unroll
    for (int k = 32; k >= 1; k >>= 1) v += __shfl_xor(v, k, 64);
    return v;
}
// broadcast a packed half2 (as 32b) from a given lane — v_readlane, stays on VALU/SALU
__device__ __forceinline__ half2_t bcast_h2(half2_t v, int lane) {
    int u = __builtin_amdgcn_readlane(__builtin_bit_cast(int, v), lane);
    return __builtin_bit_cast(half2_t, u);
}

__global__ __launch_bounds__(64, 1) void crf_nll_kernel(
    const float* __restrict__ feat,    // (B, T, N)
    const float* __restrict__ trans,   // (N, N)
    const int*   __restrict__ tags,    // (B, T)
    const int*   __restrict__ mask,    // (B, T)
    float* __restrict__ out)           // (B,)
{
    const int b    = blockIdx.x;
    const int lane = threadIdx.x;     // lane == state j
    const int j    = lane;
    const int jj   = (j < NS) ? j : 0;

    // --- E column j packed as f16 pairs over the contraction index i:
    //     Ec[m] = (exp(trans[2m][j]), exp(trans[2m+1][j]))
    // exp(-10000) == 0 exactly -> forbidden transitions vanish.
    // 25 half2 = 25 VGPRs: small enough to stay register-resident.
    half2_t Ec[25];
    #pragma unroll
    for (int m = 0; m < 25; ++m) {
        float e0 = __expf(trans[(2 * m + 0) * NS + jj]);
        float e1 = __expf(trans[(2 * m + 1) * NS + jj]);
        if (j >= NS) { e0 = 0.0f; e1 = 0.0f; }
        Ec[m] = pk_h2(e0, e1);
    }

    // --- sequence length (mask is a prefix of ones); uniform across wave ---
    int cnt = 0;
    for (int t = lane; t < TT; t += 64) cnt += mask[b * TT + t];
    const int len = wave_sum_i(cnt);

    const float* fb = feat + (size_t)b * TT * NS;

    // --- alpha init ---
    float a   = (j < NS) ? (trans[j] + fb[jj]) : -INFINITY;
    float off = wave_max_f(a);   // exact max once; afterwards tracked via lane 7

    // one forward step (all operands register-resident)
    auto step = [&](float f) {
        float p = __expf(a - off);           // bounded by off-tracking; fits f16 (RTZ, no inf)
        // lane 2m gets p from lane 2m+1 via DPP quad_perm [1,0,3,2] (cheap VALU)
        int pn = __builtin_amdgcn_update_dpp(
            __float_as_int(p), __float_as_int(p), 0xB1, 0xF, 0xF, true);
        half2_t pp = pk_h2(p, __int_as_float(pn)); // valid in even lanes
        float s0 = 0.f, s1 = 0.f, s2 = 0.f, s3 = 0.f;
        #pragma unroll
        for (int m = 0; m < 24; m += 4) {
            s0 = __builtin_amdgcn_fdot2(bcast_h2(pp, 2 * (m + 0)), Ec[m + 0], s0, false);
            s1 = __builtin_amdgcn_fdot2(bcast_h2(pp, 2 * (m + 1)), Ec[m + 1], s1, false);
            s2 = __builtin_amdgcn_fdot2(bcast_h2(pp, 2 * (m + 2)), Ec[m + 2], s2, false);
            s3 = __builtin_amdgcn_fdot2(bcast_h2(pp, 2 * (m + 3)), Ec[m + 3], s3, false);
        }
        s0 = __builtin_amdgcn_fdot2(bcast_h2(pp, 48), Ec[24], s0, false);
        float s = (s0 + s1) + (s2 + s3);
        // lanes >= 50 and dead states: s == 0 -> -inf, stays dead. Correct.
        a = f + off + __logf(s);
        // new offset: alpha spread across states is bounded (~12, non-accumulating),
        // so a_7 + 2 keeps exp(a - off) within f16 range. State 7 is never -inf.
        off = __int_as_float(__builtin_amdgcn_readlane(__float_as_int(a), 7)) + 2.0f;
    };

    // --- deep prefetch: rotating 8-register buffer of the feature stream ---
    float F[8];
    #pragma unroll
    for (int d = 0; d < 8; ++d) F[d] = fb[(1 + d) * NS + jj];

    int t = 1;
    for (; t + 8 <= len; t += 8) {
        #pragma unroll
        for (int u = 0; u < 8; ++u) {
            float f = F[u];
            int tl = t + u + 8;
            tl = (tl < TT) ? tl : TT - 1;   // clamp; overshoot loads are discarded
            F[u] = fb[tl * NS + jj];        // 8 loads in flight -> HBM latency hidden
            step(f);
        }
    }
    // tail (< 8 steps): reload directly — these lines are L1-hot from the prefetch
    for (; t < len; ++t) {
        float f = fb[t * NS + jj];
        step(f);
    }

    // --- log_z = logsumexp_j(alpha[j] + trans[j][END=1]) ---
    float v = (j < NS) ? (a + trans[j * NS + 1]) : -INFINITY;
    float M = wave_max_f(v);
    float Z = wave_sum_f(__expf(v - M));
    float log_z = M + __logf(Z);

    // --- gold path score, lane-parallel over t ---
    const int* tb = tags + (size_t)b * TT;
    float sc = 0.0f;
    for (int t2 = lane; t2 < len; t2 += 64) {
        int tg = tb[t2];
        sc += fb[t2 * NS + tg];
        if (t2 >= 1) sc += trans[tb[t2 - 1] * NS + tg];
    }
    sc = wave_sum_f(sc);

    if (lane == 0) {
        int t0 = tb[0];
        int tl = tb[len - 1];
        sc += trans[t0] + trans[tl * NS + 1];
        out[b] = log_z - sc;
    }
}

extern "C" void kernel_launch(void* const* d_in, const int* in_sizes, int n_in,
                              void* d_out, int out_size, void* d_ws, size_t ws_size,
                              hipStream_t stream) {
    const float* feat  = (const float*)d_in[0];
    const float* trans = (const float*)d_in[1];
    const int*   tags  = (const int*)d_in[2];
    const int*   mask  = (const int*)d_in[3];
    float* out = (float*)d_out;
    crf_nll_kernel<<<dim3(BB), dim3(64), 0, stream>>>(feat, trans, tags, mask, out);
}

// Round 4
// 356.959 us; speedup vs baseline: 1.5670x; 1.2329x over previous
//
#include <hip/hip_runtime.h>
#include <math.h>

#define BB 512
#define TT 1024
#define NS 50

typedef _Float16 half2_t __attribute__((ext_vector_type(2)));

static __device__ __forceinline__ half2_t pk_h2(float a, float b) {
    auto r = __builtin_amdgcn_cvt_pkrtz(a, b);   // __fp16x2 -> bit-cast for fdot2
    return __builtin_bit_cast(half2_t, r);
}
static __device__ __forceinline__ float wave_max_f(float v) {
    #pragma unroll
    for (int k = 32; k >= 1; k >>= 1) v = fmaxf(v, __shfl_xor(v, k, 64));
    return v;
}
static __device__ __forceinline__ float wave_sum_f(float v) {
    #pragma unroll
    for (int k = 32; k >= 1; k >>= 1) v += __shfl_xor(v, k, 64);
    return v;
}
static __device__ __forceinline__ int wave_sum_i(int v) {
    #pragma unroll
    for (int k = 32; k >= 1; k >>= 1) v += __shfl_xor(v, k, 64);
    return v;
}
static __device__ __forceinline__ half2_t bcast_h2(half2_t v, int lane) {
    int u = __builtin_amdgcn_readlane(__builtin_bit_cast(int, v), lane);
    return __builtin_bit_cast(half2_t, u);
}

__global__ __launch_bounds__(64, 1) void crf_nll_kernel(
    const float* __restrict__ feat,    // (B, T, N)
    const float* __restrict__ trans,   // (N, N)
    const int*   __restrict__ tags,    // (B, T)
    const int*   __restrict__ mask,    // (B, T)
    float* __restrict__ out)           // (B,)
{
    const int b    = blockIdx.x;
    const int lane = threadIdx.x;     // lane == state j
    const int j    = lane;
    const int jj   = (j < NS) ? j : 0;

    // --- E column j as 25 NAMED packed-f16 registers (no array -> no scratch demotion).
    // Ec_m = (exp(trans[2m][j]), exp(trans[2m+1][j])); exp(-10000)==0 kills forbidden.
#define INIT_E(m) half2_t e##m; { \
        float x0 = __expf(trans[(2*m + 0) * NS + jj]); \
        float x1 = __expf(trans[(2*m + 1) * NS + jj]); \
        if (j >= NS) { x0 = 0.0f; x1 = 0.0f; } \
        e##m = pk_h2(x0, x1); }
    INIT_E(0)  INIT_E(1)  INIT_E(2)  INIT_E(3)  INIT_E(4)
    INIT_E(5)  INIT_E(6)  INIT_E(7)  INIT_E(8)  INIT_E(9)
    INIT_E(10) INIT_E(11) INIT_E(12) INIT_E(13) INIT_E(14)
    INIT_E(15) INIT_E(16) INIT_E(17) INIT_E(18) INIT_E(19)
    INIT_E(20) INIT_E(21) INIT_E(22) INIT_E(23) INIT_E(24)
#undef INIT_E

    // --- sequence length (mask is a prefix of ones); uniform across wave ---
    int cnt = 0;
    for (int t = lane; t < TT; t += 64) cnt += mask[b * TT + t];
    const int len = wave_sum_i(cnt);

    const float* fb = feat + (size_t)b * TT * NS;

    // --- alpha init ---
    float a   = (j < NS) ? (trans[j] + fb[jj]) : -INFINITY;
    float off = wave_max_f(a);

    // one forward step; captures only SCALARS (SSA-safe)
    auto step = [&](float f) {
        float p = __expf(a - off);
        int pn = __builtin_amdgcn_update_dpp(
            __float_as_int(p), __float_as_int(p), 0xB1, 0xF, 0xF, true);
        half2_t pp = pk_h2(p, __int_as_float(pn));   // lane 2m: (p_{2m}, p_{2m+1})
#define DOT(acc, m) acc = __builtin_amdgcn_fdot2(bcast_h2(pp, 2*(m)), e##m, acc, false)
        float s0 = 0.f, s1 = 0.f, s2 = 0.f, s3 = 0.f;
        float s4 = 0.f, s5 = 0.f, s6 = 0.f, s7 = 0.f;
        DOT(s0, 0);  DOT(s1, 1);  DOT(s2, 2);  DOT(s3, 3);
        DOT(s4, 4);  DOT(s5, 5);  DOT(s6, 6);  DOT(s7, 7);
        DOT(s0, 8);  DOT(s1, 9);  DOT(s2, 10); DOT(s3, 11);
        DOT(s4, 12); DOT(s5, 13); DOT(s6, 14); DOT(s7, 15);
        DOT(s0, 16); DOT(s1, 17); DOT(s2, 18); DOT(s3, 19);
        DOT(s4, 20); DOT(s5, 21); DOT(s6, 22); DOT(s7, 23);
        DOT(s0, 24);
#undef DOT
        float s = ((s0 + s1) + (s2 + s3)) + ((s4 + s5) + (s6 + s7));
        // dead lanes/states: s == 0 -> -inf, stays dead. Correct.
        a = f + off + __logf(s);
        // off tracked via state 7 (never -inf); spread bounded, non-accumulating.
        off = __int_as_float(__builtin_amdgcn_readlane(__float_as_int(a), 7)) + 2.0f;
    };

    // --- depth-8 prefetch in NAMED registers, hand-unrolled x8 main loop ---
    float q0 = fb[1 * NS + jj], q1 = fb[2 * NS + jj];
    float q2 = fb[3 * NS + jj], q3 = fb[4 * NS + jj];
    float q4 = fb[5 * NS + jj], q5 = fb[6 * NS + jj];
    float q6 = fb[7 * NS + jj], q7 = fb[8 * NS + jj];

#define PF_STEP(qr, d) { \
        float f = qr; \
        int tl = t + 8 + (d); tl = (tl < TT) ? tl : (TT - 1); \
        qr = fb[(size_t)tl * NS + jj]; \
        step(f); }

    int t = 1;
    for (; t + 8 <= len; t += 8) {
        PF_STEP(q0, 0) PF_STEP(q1, 1) PF_STEP(q2, 2) PF_STEP(q3, 3)
        PF_STEP(q4, 4) PF_STEP(q5, 5) PF_STEP(q6, 6) PF_STEP(q7, 7)
    }
#undef PF_STEP
    // tail (<8 steps): rows are L1-hot from the prefetch overshoot
    for (; t < len; ++t) {
        float f = fb[(size_t)t * NS + jj];
        step(f);
    }

    // --- log_z = logsumexp_j(alpha[j] + trans[j][END=1]) ---
    float v = (j < NS) ? (a + trans[j * NS + 1]) : -INFINITY;
    float M = wave_max_f(v);
    float Z = wave_sum_f(__expf(v - M));
    float log_z = M + __logf(Z);

    // --- gold path score, lane-parallel over t ---
    const int* tb = tags + (size_t)b * TT;
    float sc = 0.0f;
    for (int t2 = lane; t2 < len; t2 += 64) {
        int tg = tb[t2];
        sc += fb[(size_t)t2 * NS + tg];
        if (t2 >= 1) sc += trans[tb[t2 - 1] * NS + tg];
    }
    sc = wave_sum_f(sc);

    if (lane == 0) {
        int t0 = tb[0];
        int tl = tb[len - 1];
        sc += trans[t0] + trans[tl * NS + 1];
        out[b] = log_z - sc;
    }
}

extern "C" void kernel_launch(void* const* d_in, const int* in_sizes, int n_in,
                              void* d_out, int out_size, void* d_ws, size_t ws_size,
                              hipStream_t stream) {
    const float* feat  = (const float*)d_in[0];
    const float* trans = (const float*)d_in[1];
    const int*   tags  = (const int*)d_in[2];
    const int*   mask  = (const int*)d_in[3];
    float* out = (float*)d_out;
    crf_nll_kernel<<<dim3(BB), dim3(64), 0, stream>>>(feat, trans, tags, mask, out);
}